// Round 4
// baseline (227.550 us; speedup 1.0000x reference)
//
#include <hip/hip_runtime.h>
#include <hip/hip_bf16.h>
#include <stdint.h>

#define B_   2
#define C_   256
#define P_   4096   // H*W = 64*64
#define N_   8
#define OUTC 2592   // N_ * 324

typedef __bf16 bf16x8 __attribute__((ext_vector_type(8)));
typedef float floatx4 __attribute__((ext_vector_type(4)));

// ---------------- fmap (B,C,P) fp32 -> (B,P,C) bf16 ----------------
__global__ void conv_t(const float* __restrict__ in, __hip_bfloat16* __restrict__ out) {
    __shared__ float tile[32][33];
    int b  = blockIdx.z;
    int p0 = blockIdx.x * 32;
    int c0 = blockIdx.y * 32;
    int tx = threadIdx.x;   // 0..31
    int ty0 = threadIdx.y;  // 0..7
    const float* ip = in + ((size_t)b * C_ + c0) * P_ + p0;
    for (int r = 0; r < 4; r++) {
        int ty = ty0 + r * 8;
        tile[ty][tx] = ip[(size_t)ty * P_ + tx];
    }
    __syncthreads();
    __hip_bfloat16* op = out + ((size_t)b * P_ + p0) * C_ + c0;
    for (int r = 0; r < 4; r++) {
        int ty = ty0 + r * 8;
        op[(size_t)ty * C_ + tx] = __float2bfloat16(tile[tx][ty]);
    }
}

// ---------------- corr GEMM: corr[p][q] = sum_c A[p][c]*B[q][c] / 16 ----------------
__global__ __launch_bounds__(256) void gemm_corr(const __hip_bfloat16* __restrict__ A,
                                                 const __hip_bfloat16* __restrict__ Bm,
                                                 float* __restrict__ Cmat) {
    __shared__ __align__(16) __hip_bfloat16 lA[128 * 32];
    __shared__ __align__(16) __hip_bfloat16 lB[128 * 32];
    const int b  = blockIdx.z;
    const int m0 = blockIdx.y * 128;
    const int n0 = blockIdx.x * 128;
    const __hip_bfloat16* Ab = A  + (size_t)b * P_ * C_;
    const __hip_bfloat16* Bb = Bm + (size_t)b * P_ * C_;
    float* Cb = Cmat + (size_t)b * P_ * P_;

    const int tid  = threadIdx.x;
    const int lane = tid & 63;
    const int w    = tid >> 6;       // 0..3
    const int wm   = w & 1, wn = w >> 1;

    floatx4 acc[4][4];
    for (int i = 0; i < 4; i++)
        for (int j = 0; j < 4; j++)
            acc[i][j] = floatx4{0.f, 0.f, 0.f, 0.f};

    const int srow = w * 16 + (lane >> 2);   // row within quarter-tile
    const int scol = (lane & 3) * 8;         // k element offset (8 bf16 = 16B)

    for (int k0 = 0; k0 < C_; k0 += 32) {
        for (int j = 0; j < 2; j++) {
            int row = j * 64 + srow;
            const __hip_bfloat16* ga = Ab + (size_t)(m0 + row) * C_ + k0 + scol;
            const __hip_bfloat16* gb = Bb + (size_t)(n0 + row) * C_ + k0 + scol;
            // wave-uniform LDS base; HW scatters base + lane*16B (= lane*8 elems)
            __hip_bfloat16* la = lA + (j * 64 + w * 16) * 32;
            __hip_bfloat16* lb = lB + (j * 64 + w * 16) * 32;
            __builtin_amdgcn_global_load_lds((const __attribute__((address_space(1))) void*)ga,
                                             (__attribute__((address_space(3))) void*)la, 16, 0, 0);
            __builtin_amdgcn_global_load_lds((const __attribute__((address_space(1))) void*)gb,
                                             (__attribute__((address_space(3))) void*)lb, 16, 0, 0);
        }
        __syncthreads();
        const int kq   = (lane >> 4) * 8;  // k sub-block per lane group
        const int rsel = lane & 15;
        bf16x8 af[4], bfv[4];
        for (int i = 0; i < 4; i++) {
            af[i]  = *(const bf16x8*)&lA[(wm * 64 + i * 16 + rsel) * 32 + kq];
            bfv[i] = *(const bf16x8*)&lB[(wn * 64 + i * 16 + rsel) * 32 + kq];
        }
        for (int i = 0; i < 4; i++)
            for (int j = 0; j < 4; j++)
                acc[i][j] = __builtin_amdgcn_mfma_f32_16x16x32_bf16(af[i], bfv[j], acc[i][j], 0, 0, 0);
        __syncthreads();
    }

    // epilogue: C/D layout col=lane&15, row=(lane>>4)*4+reg (verified m89/m91)
    const float scale = 0.0625f;  // 1/sqrt(256)
    const int colb  = n0 + wn * 64 + (lane & 15);
    const int rbase = m0 + wm * 64 + ((lane >> 4) * 4);
    for (int i = 0; i < 4; i++)
        for (int j = 0; j < 4; j++)
            for (int r = 0; r < 4; r++)
                Cb[(size_t)(rbase + i * 16 + r) * P_ + colb + j * 16] = acc[i][j][r] * scale;
}

// ---------------- 2x2 avg pool over last two dims ----------------
__global__ void pool2(const float* __restrict__ in, float* __restrict__ out,
                      int win, int wout, int total_out) {
    int idx = blockIdx.x * blockDim.x + threadIdx.x;
    if (idx >= total_out) return;
    int x = idx % wout;
    int t = idx / wout;
    int y = t % wout;
    int s = t / wout;
    const float* ip = in + ((size_t)s * win + 2 * y) * win + 2 * x;
    out[idx] = 0.25f * (ip[0] + ip[1] + ip[win] + ip[win + 1]);
}

// ---------------- bilinear pyramid sampling, one block per (b,h,w) ----------------
// Output is the reference's RAW ROW-MAJOR reshape: flat layout (b, n, h, w, c=324),
// i.e. out[((b*8+n)*4096 + p)*324 + c] — channels fastest, NOT channel planes.
__global__ __launch_bounds__(256) void sample_k(const float* __restrict__ c0,
                                                const float* __restrict__ c1,
                                                const float* __restrict__ c2,
                                                const float* __restrict__ c3,
                                                const float* __restrict__ coords,
                                                float* __restrict__ outp) {
    __shared__ __align__(16) float sl[5440];  // 4096 + 1024 + 256 + 64
    __shared__ float cs[16];
    const int bp = blockIdx.x;     // b*4096 + p
    const int b  = bp >> 12;
    const int p  = bp & 4095;
    const int tid = threadIdx.x;

    {   // stage this pixel's 4-level slice into LDS (coalesced float4)
        const float4* s0 = (const float4*)(c0 + (size_t)bp * 4096);
        float4* d0 = (float4*)sl;
        for (int i = tid; i < 1024; i += 256) d0[i] = s0[i];
        const float4* s1 = (const float4*)(c1 + (size_t)bp * 1024);
        ((float4*)(sl + 4096))[tid] = s1[tid];  // 256 float4
        if (tid < 64) ((float4*)(sl + 5120))[tid] = ((const float4*)(c2 + (size_t)bp * 256))[tid];
        if (tid < 16) ((float4*)(sl + 5376))[tid] = ((const float4*)(c3 + (size_t)bp * 64))[tid];
        if (tid < 16) cs[tid] = coords[(size_t)(b * 16 + tid) * 4096 + p];
    }
    __syncthreads();

    for (int o = tid; o < OUTC; o += 256) {
        int n  = o / 324;
        int r  = o - n * 324;
        int l  = r / 81;
        int k  = r - l * 81;
        int i9 = k / 9;           // FIRST mesh index -> drives x (meshgrid ij quirk)
        int j9 = k - i9 * 9;      // second index -> drives y
        float cx = cs[n * 2 + 0];
        float cy = cs[n * 2 + 1];
        float inv = 1.0f / (float)(1 << l);
        int wl = 64 >> l;
        float mx = (float)(wl - 1);
        float x = fminf(fmaxf(cx * inv + (float)(i9 - 4), 0.0f), mx);
        float y = fminf(fmaxf(cy * inv + (float)(j9 - 4), 0.0f), mx);
        float x0f = floorf(x), y0f = floorf(y);
        float fx = x - x0f, fy = y - y0f;
        int x0 = (int)x0f, y0 = (int)y0f;
        int x1 = min(x0 + 1, wl - 1);
        int y1 = min(y0 + 1, wl - 1);
        int off = (l == 0) ? 0 : (l == 1) ? 4096 : (l == 2) ? 5120 : 5376;
        const float* base = sl + off;
        float v00 = base[y0 * wl + x0];
        float v01 = base[y0 * wl + x1];
        float v10 = base[y1 * wl + x0];
        float v11 = base[y1 * wl + x1];
        float v = v00 * (1.f - fy) * (1.f - fx) + v01 * (1.f - fy) * fx
                + v10 * fy * (1.f - fx)         + v11 * fy * fx;
        // raw row-major reshape layout: (b, n, h, w, c) with c fastest
        outp[((size_t)(b * 8 + n) * 4096 + p) * 324 + r] = v;
    }
}

extern "C" void kernel_launch(void* const* d_in, const int* in_sizes, int n_in,
                              void* d_out, int out_size, void* d_ws, size_t ws_size,
                              hipStream_t stream) {
    const float* fmap1  = (const float*)d_in[0];
    const float* fmap2  = (const float*)d_in[1];
    const float* coords = (const float*)d_in[2];
    float* out = (float*)d_out;

    char* ws = (char*)d_ws;
    size_t off = 0;
    auto alloc = [&](size_t bytes) {
        void* ptr = ws + off;
        off += (bytes + 255) & ~(size_t)255;
        return ptr;
    };
    __hip_bfloat16* f1t = (__hip_bfloat16*)alloc((size_t)B_ * P_ * C_ * 2);
    __hip_bfloat16* f2t = (__hip_bfloat16*)alloc((size_t)B_ * P_ * C_ * 2);
    float* corr0 = (float*)alloc((size_t)B_ * P_ * 4096 * 4);
    float* corr1 = (float*)alloc((size_t)B_ * P_ * 1024 * 4);
    float* corr2 = (float*)alloc((size_t)B_ * P_ * 256 * 4);
    float* corr3 = (float*)alloc((size_t)B_ * P_ * 64 * 4);

    dim3 tb(32, 8);
    conv_t<<<dim3(128, 8, B_), tb, 0, stream>>>(fmap1, f1t);
    conv_t<<<dim3(128, 8, B_), tb, 0, stream>>>(fmap2, f2t);

    gemm_corr<<<dim3(32, 32, B_), dim3(256), 0, stream>>>(f1t, f2t, corr0);

    int t1 = B_ * P_ * 32 * 32;
    int t2 = B_ * P_ * 16 * 16;
    int t3 = B_ * P_ * 8 * 8;
    pool2<<<(t1 + 255) / 256, 256, 0, stream>>>(corr0, corr1, 64, 32, t1);
    pool2<<<(t2 + 255) / 256, 256, 0, stream>>>(corr1, corr2, 32, 16, t2);
    pool2<<<(t3 + 255) / 256, 256, 0, stream>>>(corr2, corr3, 16, 8, t3);

    sample_k<<<B_ * P_, 256, 0, stream>>>(corr0, corr1, corr2, corr3, coords, out);
}

// Round 5
// 189.337 us; speedup vs baseline: 1.2018x; 1.2018x over previous
//
#include <hip/hip_runtime.h>
#include <hip/hip_bf16.h>
#include <stdint.h>

#define B_   2
#define C_   256
#define P_   4096   // H*W = 64*64
#define N_   8
#define OUTC 2592   // N_ * 324

typedef __bf16 bf16x8 __attribute__((ext_vector_type(8)));
typedef float floatx4 __attribute__((ext_vector_type(4)));

__device__ __forceinline__ float bf2f(unsigned int u16) {
    union { unsigned int i; float f; } x; x.i = u16 << 16; return x.f;
}
__device__ __forceinline__ unsigned int f2bf(float f) {
    union { float f; unsigned int i; } x; x.f = f;
    unsigned int u = x.i + 0x7FFFu + ((x.i >> 16) & 1u);  // RNE
    return u >> 16;
}

// ---------------- fmap (B,C,P) fp32 -> (B,P,C) bf16 ----------------
__global__ void conv_t(const float* __restrict__ in, __hip_bfloat16* __restrict__ out) {
    __shared__ float tile[32][33];
    int b  = blockIdx.z;
    int p0 = blockIdx.x * 32;
    int c0 = blockIdx.y * 32;
    int tx = threadIdx.x;   // 0..31
    int ty0 = threadIdx.y;  // 0..7
    const float* ip = in + ((size_t)b * C_ + c0) * P_ + p0;
    for (int r = 0; r < 4; r++) {
        int ty = ty0 + r * 8;
        tile[ty][tx] = ip[(size_t)ty * P_ + tx];
    }
    __syncthreads();
    __hip_bfloat16* op = out + ((size_t)b * P_ + p0) * C_ + c0;
    for (int r = 0; r < 4; r++) {
        int ty = ty0 + r * 8;
        op[(size_t)ty * C_ + tx] = __float2bfloat16(tile[tx][ty]);
    }
}

// ---------------- corr GEMM: corr[p][q] = sum_c A[p][c]*B[q][c] / 16, bf16 out ----------------
__global__ __launch_bounds__(256) void gemm_corr(const __hip_bfloat16* __restrict__ A,
                                                 const __hip_bfloat16* __restrict__ Bm,
                                                 unsigned short* __restrict__ Cmat) {
    __shared__ __align__(16) __hip_bfloat16 lA[128 * 32];
    __shared__ __align__(16) __hip_bfloat16 lB[128 * 32];
    const int b  = blockIdx.z;
    const int m0 = blockIdx.y * 128;
    const int n0 = blockIdx.x * 128;
    const __hip_bfloat16* Ab = A  + (size_t)b * P_ * C_;
    const __hip_bfloat16* Bb = Bm + (size_t)b * P_ * C_;
    unsigned short* Cb = Cmat + (size_t)b * P_ * P_;

    const int tid  = threadIdx.x;
    const int lane = tid & 63;
    const int w    = tid >> 6;       // 0..3
    const int wm   = w & 1, wn = w >> 1;

    floatx4 acc[4][4];
    for (int i = 0; i < 4; i++)
        for (int j = 0; j < 4; j++)
            acc[i][j] = floatx4{0.f, 0.f, 0.f, 0.f};

    const int srow = w * 16 + (lane >> 2);
    const int scol = (lane & 3) * 8;

    for (int k0 = 0; k0 < C_; k0 += 32) {
        for (int j = 0; j < 2; j++) {
            int row = j * 64 + srow;
            const __hip_bfloat16* ga = Ab + (size_t)(m0 + row) * C_ + k0 + scol;
            const __hip_bfloat16* gb = Bb + (size_t)(n0 + row) * C_ + k0 + scol;
            __hip_bfloat16* la = lA + (j * 64 + w * 16) * 32;
            __hip_bfloat16* lb = lB + (j * 64 + w * 16) * 32;
            __builtin_amdgcn_global_load_lds((const __attribute__((address_space(1))) void*)ga,
                                             (__attribute__((address_space(3))) void*)la, 16, 0, 0);
            __builtin_amdgcn_global_load_lds((const __attribute__((address_space(1))) void*)gb,
                                             (__attribute__((address_space(3))) void*)lb, 16, 0, 0);
        }
        __syncthreads();
        const int kq   = (lane >> 4) * 8;
        const int rsel = lane & 15;
        bf16x8 af[4], bfv[4];
        for (int i = 0; i < 4; i++) {
            af[i]  = *(const bf16x8*)&lA[(wm * 64 + i * 16 + rsel) * 32 + kq];
            bfv[i] = *(const bf16x8*)&lB[(wn * 64 + i * 16 + rsel) * 32 + kq];
        }
        for (int i = 0; i < 4; i++)
            for (int j = 0; j < 4; j++)
                acc[i][j] = __builtin_amdgcn_mfma_f32_16x16x32_bf16(af[i], bfv[j], acc[i][j], 0, 0, 0);
        __syncthreads();
    }

    const float scale = 0.0625f;  // 1/sqrt(256)
    const int colb  = n0 + wn * 64 + (lane & 15);
    const int rbase = m0 + wm * 64 + ((lane >> 4) * 4);
    for (int i = 0; i < 4; i++)
        for (int j = 0; j < 4; j++)
            for (int r = 0; r < 4; r++)
                Cb[(size_t)(rbase + i * 16 + r) * P_ + colb + j * 16] =
                    (unsigned short)f2bf(acc[i][j][r] * scale);
}

// ---------------- 2x2 avg pool, packed bf16 pairs, 2 outputs/thread ----------------
template<int WIN, int WOUT>
__global__ void pool2b(const unsigned int* __restrict__ in, unsigned int* __restrict__ out,
                       int npair) {
    int i = blockIdx.x * blockDim.x + threadIdx.x;
    if (i >= npair) return;
    int e = i * 2;                        // first output element (bf16 index)
    int x = e & (WOUT - 1);
    int y = (e / WOUT) & (WOUT - 1);
    int s = e / (WOUT * WOUT);
    int rowu = ((s * WIN + 2 * y) * WIN) / 2 + x;   // uint index, input row 2y
    unsigned int a0 = in[rowu],            a1 = in[rowu + 1];
    unsigned int b0 = in[rowu + WIN / 2],  b1 = in[rowu + WIN / 2 + 1];
    float s0 = 0.25f * (bf2f(a0 & 0xffff) + bf2f(a0 >> 16) + bf2f(b0 & 0xffff) + bf2f(b0 >> 16));
    float s1 = 0.25f * (bf2f(a1 & 0xffff) + bf2f(a1 >> 16) + bf2f(b1 & 0xffff) + bf2f(b1 >> 16));
    out[i] = f2bf(s0) | (f2bf(s1) << 16);
}

// ---------------- bilinear pyramid sampling, one block per (b,h,w) ----------------
// LDS pyramid rows padded to odd strides (65/33/17/9) -> bank-conflict-free.
// Per-(n,level,offset) bilinear setup precomputed into tables (288 entries).
__global__ __launch_bounds__(256) void sample_k(const unsigned short* __restrict__ c0,
                                                const unsigned short* __restrict__ c1,
                                                const unsigned short* __restrict__ c2,
                                                const unsigned short* __restrict__ c3,
                                                const float* __restrict__ coords,
                                                float* __restrict__ outp) {
    __shared__ float sl[5560];            // 65*64 + 33*32 + 17*16 + 9*8
    __shared__ float cs[16];
    __shared__ unsigned int xtp[288];     // (x0<<8)|x1
    __shared__ float        xtf[288];     // fx
    __shared__ unsigned int ytp[288];     // (y0*pw)<<16 | (y1*pw)
    __shared__ float        ytf[288];     // fy
    __shared__ unsigned int ctb[324];     // (lds_off<<16)|(tix<<8)|tiy

    const int bp = blockIdx.x;     // b*4096 + p
    const int b  = bp >> 12;
    const int p  = bp & 4095;
    const int tid = threadIdx.x;

    // ---- stage pyramid (bf16 -> fp32 into padded LDS) ----
    {
        const uint2* g0 = (const uint2*)(c0 + (size_t)bp * 4096);  // 1024 uint2
        for (int i = tid; i < 1024; i += 256) {
            uint2 v = g0[i];
            int e = i * 4, x = e & 63, y = e >> 6;
            float* d = sl + y * 65 + x;
            d[0] = bf2f(v.x & 0xffff); d[1] = bf2f(v.x >> 16);
            d[2] = bf2f(v.y & 0xffff); d[3] = bf2f(v.y >> 16);
        }
        const uint2* g1 = (const uint2*)(c1 + (size_t)bp * 1024);  // 256 uint2
        {
            uint2 v = g1[tid];
            int e = tid * 4, x = e & 31, y = e >> 5;
            float* d = sl + 4160 + y * 33 + x;
            d[0] = bf2f(v.x & 0xffff); d[1] = bf2f(v.x >> 16);
            d[2] = bf2f(v.y & 0xffff); d[3] = bf2f(v.y >> 16);
        }
        if (tid < 64) {
            uint2 v = ((const uint2*)(c2 + (size_t)bp * 256))[tid];
            int e = tid * 4, x = e & 15, y = e >> 4;
            float* d = sl + 5216 + y * 17 + x;
            d[0] = bf2f(v.x & 0xffff); d[1] = bf2f(v.x >> 16);
            d[2] = bf2f(v.y & 0xffff); d[3] = bf2f(v.y >> 16);
        }
        if (tid < 16) {
            uint2 v = ((const uint2*)(c3 + (size_t)bp * 64))[tid];
            int e = tid * 4, x = e & 7, y = e >> 3;
            float* d = sl + 5488 + y * 9 + x;
            d[0] = bf2f(v.x & 0xffff); d[1] = bf2f(v.x >> 16);
            d[2] = bf2f(v.y & 0xffff); d[3] = bf2f(v.y >> 16);
        }
        if (tid < 16) cs[tid] = coords[(size_t)(b * 16 + tid) * 4096 + p];
    }
    __syncthreads();

    // ---- build tables ----
    for (int t = tid; t < 324; t += 256) {
        if (t < 288) {
            int n = t / 36, rem = t - n * 36;
            int l = rem / 9, dd = rem - l * 9;
            int wl = 64 >> l;
            int pw = (l == 0) ? 65 : (l == 1) ? 33 : (l == 2) ? 17 : 9;
            float inv = 1.0f / (float)(1 << l);
            float mx = (float)(wl - 1);
            float cx = cs[n * 2 + 0], cy = cs[n * 2 + 1];
            float xx = fminf(fmaxf(cx * inv + (float)(dd - 4), 0.0f), mx);
            float yy = fminf(fmaxf(cy * inv + (float)(dd - 4), 0.0f), mx);
            float x0f = floorf(xx), y0f = floorf(yy);
            int x0 = (int)x0f, y0 = (int)y0f;
            int x1 = min(x0 + 1, wl - 1), y1 = min(y0 + 1, wl - 1);
            xtp[t] = ((unsigned int)x0 << 8) | (unsigned int)x1;
            xtf[t] = xx - x0f;
            ytp[t] = ((unsigned int)(y0 * pw) << 16) | (unsigned int)(y1 * pw);
            ytf[t] = yy - y0f;
        }
        // c -> (level offset, table indices); c order: l*81 + i9*9 + j9 (i9->x, j9->y)
        int c = t;
        int l = c / 81, k = c - l * 81;
        int i9 = k / 9, j9 = k - i9 * 9;
        int off = (l == 0) ? 0 : (l == 1) ? 4160 : (l == 2) ? 5216 : 5488;
        ctb[c] = ((unsigned int)off << 16) | ((unsigned int)(l * 9 + i9) << 8)
               | (unsigned int)(l * 9 + j9);
    }
    __syncthreads();

    // ---- main loop: 2592 outputs ----
    const size_t outbase = (size_t)b * ((size_t)N_ * P_ * 324) + (size_t)p * 324;
    for (int o = tid; o < OUTC; o += 256) {
        int n = o / 324;
        int c = o - n * 324;
        unsigned int cv = ctb[c];
        int off = cv >> 16;
        int tb  = n * 36;
        unsigned int xp = xtp[tb + ((cv >> 8) & 255)];
        float        fx = xtf[tb + ((cv >> 8) & 255)];
        unsigned int yp = ytp[tb + (cv & 255)];
        float        fy = ytf[tb + (cv & 255)];
        int x0 = xp >> 8, x1 = xp & 255;
        const float* r0 = sl + off + (yp >> 16);
        const float* r1 = sl + off + (yp & 0xffff);
        float v00 = r0[x0], v01 = r0[x1];
        float v10 = r1[x0], v11 = r1[x1];
        float vx0 = v00 + fx * (v01 - v00);
        float vx1 = v10 + fx * (v11 - v10);
        float v   = vx0 + fy * (vx1 - vx0);
        outp[outbase + (size_t)n * (324 * 4095) + o] = v;
    }
}

extern "C" void kernel_launch(void* const* d_in, const int* in_sizes, int n_in,
                              void* d_out, int out_size, void* d_ws, size_t ws_size,
                              hipStream_t stream) {
    const float* fmap1  = (const float*)d_in[0];
    const float* fmap2  = (const float*)d_in[1];
    const float* coords = (const float*)d_in[2];
    float* out = (float*)d_out;

    char* ws = (char*)d_ws;
    size_t off = 0;
    auto alloc = [&](size_t bytes) {
        void* ptr = ws + off;
        off += (bytes + 255) & ~(size_t)255;
        return ptr;
    };
    __hip_bfloat16* f1t = (__hip_bfloat16*)alloc((size_t)B_ * P_ * C_ * 2);
    __hip_bfloat16* f2t = (__hip_bfloat16*)alloc((size_t)B_ * P_ * C_ * 2);
    unsigned short* corr0 = (unsigned short*)alloc((size_t)B_ * P_ * 4096 * 2);
    unsigned short* corr1 = (unsigned short*)alloc((size_t)B_ * P_ * 1024 * 2);
    unsigned short* corr2 = (unsigned short*)alloc((size_t)B_ * P_ * 256 * 2);
    unsigned short* corr3 = (unsigned short*)alloc((size_t)B_ * P_ * 64 * 2);

    dim3 tb(32, 8);
    conv_t<<<dim3(128, 8, B_), tb, 0, stream>>>(fmap1, f1t);
    conv_t<<<dim3(128, 8, B_), tb, 0, stream>>>(fmap2, f2t);

    gemm_corr<<<dim3(32, 32, B_), dim3(256), 0, stream>>>(f1t, f2t, corr0);

    int np1 = B_ * P_ * 32 * 32 / 2;
    int np2 = B_ * P_ * 16 * 16 / 2;
    int np3 = B_ * P_ * 8 * 8 / 2;
    pool2b<64, 32><<<(np1 + 255) / 256, 256, 0, stream>>>((const unsigned int*)corr0,
                                                          (unsigned int*)corr1, np1);
    pool2b<32, 16><<<(np2 + 255) / 256, 256, 0, stream>>>((const unsigned int*)corr1,
                                                          (unsigned int*)corr2, np2);
    pool2b<16, 8><<<(np3 + 255) / 256, 256, 0, stream>>>((const unsigned int*)corr2,
                                                         (unsigned int*)corr3, np3);

    sample_k<<<B_ * P_, 256, 0, stream>>>(corr0, corr1, corr2, corr3, coords, out);
}

// Round 6
// 180.152 us; speedup vs baseline: 1.2631x; 1.0510x over previous
//
#include <hip/hip_runtime.h>
#include <hip/hip_bf16.h>
#include <stdint.h>

#define B_   2
#define C_   256
#define P_   4096   // H*W = 64*64
#define N_   8
#define OUTC 2592   // N_ * 324

typedef __bf16 bf16x8 __attribute__((ext_vector_type(8)));
typedef float floatx4 __attribute__((ext_vector_type(4)));

__device__ __forceinline__ float bf2f(unsigned int u16) {
    union { unsigned int i; float f; } x; x.i = u16 << 16; return x.f;
}
__device__ __forceinline__ unsigned int f2bf(float f) {
    union { float f; unsigned int i; } x; x.f = f;
    unsigned int u = x.i + 0x7FFFu + ((x.i >> 16) & 1u);  // RNE
    return u >> 16;
}

// ---------------- fmaps (B,C,P) fp32 -> (B,P,C) bf16, both in one dispatch ----------------
__global__ void conv_both(const float* __restrict__ in1, const float* __restrict__ in2,
                          __hip_bfloat16* __restrict__ out1, __hip_bfloat16* __restrict__ out2) {
    __shared__ float tile[32][33];
    int which = blockIdx.z >> 1;
    int b  = blockIdx.z & 1;
    const float* in = which ? in2 : in1;
    __hip_bfloat16* out = which ? out2 : out1;
    int p0 = blockIdx.x * 32;
    int c0 = blockIdx.y * 32;
    int tx = threadIdx.x;   // 0..31
    int ty0 = threadIdx.y;  // 0..7
    const float* ip = in + ((size_t)b * C_ + c0) * P_ + p0;
    for (int r = 0; r < 4; r++) {
        int ty = ty0 + r * 8;
        tile[ty][tx] = ip[(size_t)ty * P_ + tx];
    }
    __syncthreads();
    __hip_bfloat16* op = out + ((size_t)b * P_ + p0) * C_ + c0;
    for (int r = 0; r < 4; r++) {
        int ty = ty0 + r * 8;
        op[(size_t)ty * C_ + tx] = __float2bfloat16(tile[tx][ty]);
    }
}

// ---------------- corr GEMM, XCD-swizzled blocks: corr[p][q] = A[p]·B[q] / 16, bf16 out ------
// swizzle: id%8 selects a 4-row m-strip; per-XCD working set (A-strip 256KB + B 2MB) fits 4MB L2.
__global__ __launch_bounds__(256) void gemm_corr(const __hip_bfloat16* __restrict__ A,
                                                 const __hip_bfloat16* __restrict__ Bm,
                                                 unsigned short* __restrict__ Cmat) {
    __shared__ __align__(16) __hip_bfloat16 lA[128 * 32];
    __shared__ __align__(16) __hip_bfloat16 lB[128 * 32];
    const int id = blockIdx.x;           // 0..2047
    const int bz = id >> 10;
    const int r_ = id & 1023;
    const int s_ = r_ >> 3;
    const int by = (r_ & 7) * 4 + (s_ >> 5);
    const int bx = s_ & 31;
    const int m0 = by * 128;
    const int n0 = bx * 128;
    const __hip_bfloat16* Ab = A  + (size_t)bz * P_ * C_;
    const __hip_bfloat16* Bb = Bm + (size_t)bz * P_ * C_;
    unsigned short* Cb = Cmat + (size_t)bz * P_ * P_;

    const int tid  = threadIdx.x;
    const int lane = tid & 63;
    const int w    = tid >> 6;       // 0..3
    const int wm   = w & 1, wn = w >> 1;

    floatx4 acc[4][4];
    for (int i = 0; i < 4; i++)
        for (int j = 0; j < 4; j++)
            acc[i][j] = floatx4{0.f, 0.f, 0.f, 0.f};

    const int srow = w * 16 + (lane >> 2);
    const int scol = (lane & 3) * 8;

    for (int k0 = 0; k0 < C_; k0 += 32) {
        for (int j = 0; j < 2; j++) {
            int row = j * 64 + srow;
            const __hip_bfloat16* ga = Ab + (size_t)(m0 + row) * C_ + k0 + scol;
            const __hip_bfloat16* gb = Bb + (size_t)(n0 + row) * C_ + k0 + scol;
            __hip_bfloat16* la = lA + (j * 64 + w * 16) * 32;
            __hip_bfloat16* lb = lB + (j * 64 + w * 16) * 32;
            __builtin_amdgcn_global_load_lds((const __attribute__((address_space(1))) void*)ga,
                                             (__attribute__((address_space(3))) void*)la, 16, 0, 0);
            __builtin_amdgcn_global_load_lds((const __attribute__((address_space(1))) void*)gb,
                                             (__attribute__((address_space(3))) void*)lb, 16, 0, 0);
        }
        __syncthreads();
        const int kq   = (lane >> 4) * 8;
        const int rsel = lane & 15;
        bf16x8 af[4], bfv[4];
        for (int i = 0; i < 4; i++) {
            af[i]  = *(const bf16x8*)&lA[(wm * 64 + i * 16 + rsel) * 32 + kq];
            bfv[i] = *(const bf16x8*)&lB[(wn * 64 + i * 16 + rsel) * 32 + kq];
        }
        for (int i = 0; i < 4; i++)
            for (int j = 0; j < 4; j++)
                acc[i][j] = __builtin_amdgcn_mfma_f32_16x16x32_bf16(af[i], bfv[j], acc[i][j], 0, 0, 0);
        __syncthreads();
    }

    const float scale = 0.0625f;  // 1/sqrt(256)
    const int colb  = n0 + wn * 64 + (lane & 15);
    const int rbase = m0 + wm * 64 + ((lane >> 4) * 4);
    for (int i = 0; i < 4; i++)
        for (int j = 0; j < 4; j++)
            for (int r = 0; r < 4; r++)
                Cb[(size_t)(rbase + i * 16 + r) * P_ + colb + j * 16] =
                    (unsigned short)f2bf(acc[i][j][r] * scale);
}

// ---------------- fused 3-level pyramid: one block per (b,p) row ----------------
// stages the 64x64 bf16 corr row in LDS, pools 64->32->16->8 in-place, writes all levels.
__global__ __launch_bounds__(256) void pyramid(const unsigned int* __restrict__ c0,
                                               unsigned int* __restrict__ c1,
                                               unsigned int* __restrict__ c2,
                                               unsigned int* __restrict__ c3) {
    __shared__ unsigned int L0[2048];   // 64x64 bf16 (32 uints/row)
    __shared__ unsigned int L1[512];    // 32x32 (16 uints/row)
    __shared__ unsigned int L2[128];    // 16x16 (8 uints/row)
    const int bp = blockIdx.x;
    const int tid = threadIdx.x;
    {
        const uint2* g = (const uint2*)(c0 + (size_t)bp * 2048);
        uint2* d = (uint2*)L0;
        for (int i = tid; i < 1024; i += 256) d[i] = g[i];
    }
    __syncthreads();
    // pool 64 -> 32 (512 packed uints)
    for (int t = tid; t < 512; t += 256) {
        int x = t & 15;            // uint col within output row... careful: out row = 16 uints
        int y = t >> 4;            // 0..31
        unsigned int a = L0[(2 * y) * 32 + 2 * x];
        unsigned int a2 = L0[(2 * y) * 32 + 2 * x + 1];
        unsigned int b = L0[(2 * y + 1) * 32 + 2 * x];
        unsigned int b2 = L0[(2 * y + 1) * 32 + 2 * x + 1];
        float s0 = 0.25f * (bf2f(a & 0xffff) + bf2f(a >> 16) + bf2f(b & 0xffff) + bf2f(b >> 16));
        float s1 = 0.25f * (bf2f(a2 & 0xffff) + bf2f(a2 >> 16) + bf2f(b2 & 0xffff) + bf2f(b2 >> 16));
        unsigned int u = f2bf(s0) | (f2bf(s1) << 16);
        L1[t] = u;
        c1[(size_t)bp * 512 + t] = u;
    }
    __syncthreads();
    // pool 32 -> 16 (128 uints)
    if (tid < 128) {
        int x = tid & 7;
        int y = tid >> 3;          // 0..15
        unsigned int a = L1[(2 * y) * 16 + 2 * x];
        unsigned int a2 = L1[(2 * y) * 16 + 2 * x + 1];
        unsigned int b = L1[(2 * y + 1) * 16 + 2 * x];
        unsigned int b2 = L1[(2 * y + 1) * 16 + 2 * x + 1];
        float s0 = 0.25f * (bf2f(a & 0xffff) + bf2f(a >> 16) + bf2f(b & 0xffff) + bf2f(b >> 16));
        float s1 = 0.25f * (bf2f(a2 & 0xffff) + bf2f(a2 >> 16) + bf2f(b2 & 0xffff) + bf2f(b2 >> 16));
        unsigned int u = f2bf(s0) | (f2bf(s1) << 16);
        L2[tid] = u;
        c2[(size_t)bp * 128 + tid] = u;
    }
    __syncthreads();
    // pool 16 -> 8 (32 uints)
    if (tid < 32) {
        int x = tid & 3;
        int y = tid >> 2;          // 0..7
        unsigned int a = L2[(2 * y) * 8 + 2 * x];
        unsigned int a2 = L2[(2 * y) * 8 + 2 * x + 1];
        unsigned int b = L2[(2 * y + 1) * 8 + 2 * x];
        unsigned int b2 = L2[(2 * y + 1) * 8 + 2 * x + 1];
        float s0 = 0.25f * (bf2f(a & 0xffff) + bf2f(a >> 16) + bf2f(b & 0xffff) + bf2f(b >> 16));
        float s1 = 0.25f * (bf2f(a2 & 0xffff) + bf2f(a2 >> 16) + bf2f(b2 & 0xffff) + bf2f(b2 >> 16));
        c3[(size_t)bp * 32 + tid] = f2bf(s0) | (f2bf(s1) << 16);
    }
}

// ---------------- bilinear pyramid sampling, one block per (b,h,w) ----------------
// pyramid staged as bf16 in LDS (strides 66/34/18/10 shorts -> odd uint stride, conflict-free).
// tables: per (n,l,offset) packed float2 {frac, indices}; row offsets pre-folded with level base.
__global__ __launch_bounds__(256) void sample_k(const unsigned short* __restrict__ c0,
                                                const unsigned short* __restrict__ c1,
                                                const unsigned short* __restrict__ c2,
                                                const unsigned short* __restrict__ c3,
                                                const float* __restrict__ coords,
                                                float* __restrict__ outp) {
    __shared__ unsigned short sl16[5680];  // 66*64 + 34*32 + 18*16 + 10*8
    __shared__ float cs[16];
    __shared__ float2 xt[288];             // {fx, bits: x0 | x1<<8}
    __shared__ float2 yt[288];             // {fy, bits: (base+y0*pw) | (base+y1*pw)<<16}
    __shared__ unsigned int ctb[324];      // (l*9+i9)<<8 | (l*9+j9)

    const int bp = blockIdx.x;     // b*4096 + p
    const int b  = bp >> 12;
    const int p  = bp & 4095;
    const int tid = threadIdx.x;
    unsigned int* slu = (unsigned int*)sl16;

    // ---- stage pyramid rows (raw bf16 copy into padded LDS) ----
    {
        const uint2* g0 = (const uint2*)(c0 + (size_t)bp * 4096);  // 1024 uint2
        for (int i = tid; i < 1024; i += 256) {
            uint2 v = g0[i];
            int e = 4 * i;                 // first element (x multiple of 4)
            int y = e >> 6, x = e & 63;
            int u = (y * 66 + x) >> 1;     // even short idx -> uint idx
            slu[u] = v.x; slu[u + 1] = v.y;
        }
        const unsigned int* g1 = (const unsigned int*)(c1 + (size_t)bp * 1024);  // 512 uints
        for (int i = tid; i < 512; i += 256)
            slu[2112 + (i >> 4) * 17 + (i & 15)] = g1[i];
        if (tid < 128)
            slu[2656 + (tid >> 3) * 9 + (tid & 7)] =
                ((const unsigned int*)(c2 + (size_t)bp * 256))[tid];
        if (tid < 32)
            slu[2800 + (tid >> 2) * 5 + (tid & 3)] =
                ((const unsigned int*)(c3 + (size_t)bp * 64))[tid];
        if (tid < 16) cs[tid] = coords[(size_t)(b * 16 + tid) * 4096 + p];
    }
    __syncthreads();

    // ---- build tables ----
    for (int t = tid; t < 324; t += 256) {
        if (t < 288) {
            int n = t / 36, rem = t - n * 36;
            int l = rem / 9, dd = rem - l * 9;
            int wl = 64 >> l;
            int pw   = (l == 0) ? 66 : (l == 1) ? 34 : (l == 2) ? 18 : 10;
            int base = (l == 0) ? 0  : (l == 1) ? 4224 : (l == 2) ? 5312 : 5600;
            float inv = 1.0f / (float)(1 << l);
            float mx = (float)(wl - 1);
            float cx = cs[n * 2 + 0], cy = cs[n * 2 + 1];
            float xx = fminf(fmaxf(cx * inv + (float)(dd - 4), 0.0f), mx);
            float yy = fminf(fmaxf(cy * inv + (float)(dd - 4), 0.0f), mx);
            float x0f = floorf(xx), y0f = floorf(yy);
            int x0 = (int)x0f, y0 = (int)y0f;
            int x1 = min(x0 + 1, wl - 1), y1 = min(y0 + 1, wl - 1);
            unsigned int xb = (unsigned int)x0 | ((unsigned int)x1 << 8);
            unsigned int yb = (unsigned int)(base + y0 * pw)
                            | ((unsigned int)(base + y1 * pw) << 16);
            xt[t] = make_float2(xx - x0f, __uint_as_float(xb));
            yt[t] = make_float2(yy - y0f, __uint_as_float(yb));
        }
        int c = t;
        int l = c / 81, k = c - l * 81;
        int i9 = k / 9, j9 = k - i9 * 9;
        ctb[c] = ((unsigned int)(l * 9 + i9) << 8) | (unsigned int)(l * 9 + j9);
    }
    __syncthreads();

    // ---- main loop: 2592 outputs ----
    const size_t outbase = (size_t)b * ((size_t)N_ * P_ * 324) + (size_t)p * 324;
    for (int o = tid; o < OUTC; o += 256) {
        int n = o / 324;
        int c = o - n * 324;
        unsigned int cv = ctb[c];
        int tb = n * 36;
        float2 xv = xt[tb + (cv >> 8)];
        float2 yv = yt[tb + (cv & 255)];
        unsigned int xb = __float_as_uint(xv.y);
        unsigned int yb = __float_as_uint(yv.y);
        int x0 = xb & 255, x1 = xb >> 8;
        int r0 = yb & 0xffff, r1 = yb >> 16;
        float fx = xv.x, fy = yv.x;
        float v00 = bf2f(sl16[r0 + x0]);
        float v01 = bf2f(sl16[r0 + x1]);
        float v10 = bf2f(sl16[r1 + x0]);
        float v11 = bf2f(sl16[r1 + x1]);
        float vx0 = v00 + fx * (v01 - v00);
        float vx1 = v10 + fx * (v11 - v10);
        float v   = vx0 + fy * (vx1 - vx0);
        outp[outbase + (size_t)n * (324 * 4095) + o] = v;
    }
}

extern "C" void kernel_launch(void* const* d_in, const int* in_sizes, int n_in,
                              void* d_out, int out_size, void* d_ws, size_t ws_size,
                              hipStream_t stream) {
    const float* fmap1  = (const float*)d_in[0];
    const float* fmap2  = (const float*)d_in[1];
    const float* coords = (const float*)d_in[2];
    float* out = (float*)d_out;

    char* ws = (char*)d_ws;
    size_t off = 0;
    auto alloc = [&](size_t bytes) {
        void* ptr = ws + off;
        off += (bytes + 255) & ~(size_t)255;
        return ptr;
    };
    __hip_bfloat16* f1t = (__hip_bfloat16*)alloc((size_t)B_ * P_ * C_ * 2);
    __hip_bfloat16* f2t = (__hip_bfloat16*)alloc((size_t)B_ * P_ * C_ * 2);
    unsigned short* corr0 = (unsigned short*)alloc((size_t)B_ * P_ * 4096 * 2);
    unsigned short* corr1 = (unsigned short*)alloc((size_t)B_ * P_ * 1024 * 2);
    unsigned short* corr2 = (unsigned short*)alloc((size_t)B_ * P_ * 256 * 2);
    unsigned short* corr3 = (unsigned short*)alloc((size_t)B_ * P_ * 64 * 2);

    conv_both<<<dim3(128, 8, 2 * B_), dim3(32, 8), 0, stream>>>(fmap1, fmap2, f1t, f2t);

    gemm_corr<<<dim3(2048), dim3(256), 0, stream>>>(f1t, f2t, corr0);

    pyramid<<<dim3(B_ * P_), dim3(256), 0, stream>>>((const unsigned int*)corr0,
                                                     (unsigned int*)corr1,
                                                     (unsigned int*)corr2,
                                                     (unsigned int*)corr3);

    sample_k<<<dim3(B_ * P_), dim3(256), 0, stream>>>(corr0, corr1, corr2, corr3, coords, out);
}

// Round 7
// 175.898 us; speedup vs baseline: 1.2936x; 1.0242x over previous
//
#include <hip/hip_runtime.h>
#include <hip/hip_bf16.h>
#include <stdint.h>

#define B_   2
#define C_   256
#define P_   4096   // H*W = 64*64
#define N_   8
#define OUTC 2592   // N_ * 324

typedef __bf16 bf16x8 __attribute__((ext_vector_type(8)));
typedef float floatx4 __attribute__((ext_vector_type(4)));

__device__ __forceinline__ float bf2f(unsigned int u16) {
    union { unsigned int i; float f; } x; x.i = u16 << 16; return x.f;
}
__device__ __forceinline__ unsigned int f2bf(float f) {
    union { float f; unsigned int i; } x; x.f = f;
    unsigned int u = x.i + 0x7FFFu + ((x.i >> 16) & 1u);  // RNE
    return u >> 16;
}

// ---------------- fmaps (B,C,P) fp32 -> (B,P,C) bf16, both in one dispatch ----------------
__global__ void conv_both(const float* __restrict__ in1, const float* __restrict__ in2,
                          __hip_bfloat16* __restrict__ out1, __hip_bfloat16* __restrict__ out2) {
    __shared__ float tile[32][33];
    int which = blockIdx.z >> 1;
    int b  = blockIdx.z & 1;
    const float* in = which ? in2 : in1;
    __hip_bfloat16* out = which ? out2 : out1;
    int p0 = blockIdx.x * 32;
    int c0 = blockIdx.y * 32;
    int tx = threadIdx.x;   // 0..31
    int ty0 = threadIdx.y;  // 0..7
    const float* ip = in + ((size_t)b * C_ + c0) * P_ + p0;
    for (int r = 0; r < 4; r++) {
        int ty = ty0 + r * 8;
        tile[ty][tx] = ip[(size_t)ty * P_ + tx];
    }
    __syncthreads();
    __hip_bfloat16* op = out + ((size_t)b * P_ + p0) * C_ + c0;
    for (int r = 0; r < 4; r++) {
        int ty = ty0 + r * 8;
        op[(size_t)ty * C_ + tx] = __float2bfloat16(tile[tx][ty]);
    }
}

// ---------------- corr GEMM + fused level-1 pool ----------------
// corr[p][q] = A[p]·B[q]/16 (bf16 out, packed u32 stores).
// Waves own 32-row strips (all 128 cols): pool quads (c,c+1,c+64,c+65) are
// (lane^1, j vs j+4) -> in-register via shfl_xor. Each block emits its q-tile's
// level-1 row segment corr1[p][bx*32 .. +32) directly from fp32 acc.
__global__ __launch_bounds__(256) void gemm_corr(const __hip_bfloat16* __restrict__ A,
                                                 const __hip_bfloat16* __restrict__ Bm,
                                                 unsigned int* __restrict__ C0,
                                                 unsigned short* __restrict__ C1) {
    __shared__ __align__(16) __hip_bfloat16 lA[128 * 32];
    __shared__ __align__(16) __hip_bfloat16 lB[128 * 32];
    const int id = blockIdx.x;           // 0..2047
    const int bz = id >> 10;
    const int r_ = id & 1023;
    const int s_ = r_ >> 3;
    const int by = (r_ & 7) * 4 + (s_ >> 5);
    const int bx = s_ & 31;
    const int m0 = by * 128;
    const int n0 = bx * 128;
    const __hip_bfloat16* Ab = A  + (size_t)bz * P_ * C_;
    const __hip_bfloat16* Bb = Bm + (size_t)bz * P_ * C_;

    const int tid  = threadIdx.x;
    const int lane = tid & 63;
    const int w    = tid >> 6;       // 0..3 -> rows w*32..w*32+31

    floatx4 acc[2][8];
    for (int i = 0; i < 2; i++)
        for (int j = 0; j < 8; j++)
            acc[i][j] = floatx4{0.f, 0.f, 0.f, 0.f};

    const int srow = w * 16 + (lane >> 2);
    const int scol = (lane & 3) * 8;

    for (int k0 = 0; k0 < C_; k0 += 32) {
        for (int j = 0; j < 2; j++) {
            int row = j * 64 + srow;
            const __hip_bfloat16* ga = Ab + (size_t)(m0 + row) * C_ + k0 + scol;
            const __hip_bfloat16* gb = Bb + (size_t)(n0 + row) * C_ + k0 + scol;
            __hip_bfloat16* la = lA + (j * 64 + w * 16) * 32;
            __hip_bfloat16* lb = lB + (j * 64 + w * 16) * 32;
            __builtin_amdgcn_global_load_lds((const __attribute__((address_space(1))) void*)ga,
                                             (__attribute__((address_space(3))) void*)la, 16, 0, 0);
            __builtin_amdgcn_global_load_lds((const __attribute__((address_space(1))) void*)gb,
                                             (__attribute__((address_space(3))) void*)lb, 16, 0, 0);
        }
        __syncthreads();
        const int kq   = (lane >> 4) * 8;
        const int rsel = lane & 15;
        bf16x8 af[2];
        for (int i = 0; i < 2; i++)
            af[i] = *(const bf16x8*)&lA[(w * 32 + i * 16 + rsel) * 32 + kq];
        for (int jh = 0; jh < 2; jh++) {
            bf16x8 bfv[4];
            for (int jj = 0; jj < 4; jj++)
                bfv[jj] = *(const bf16x8*)&lB[((jh * 4 + jj) * 16 + rsel) * 32 + kq];
            for (int i = 0; i < 2; i++)
                for (int jj = 0; jj < 4; jj++)
                    acc[i][jh * 4 + jj] =
                        __builtin_amdgcn_mfma_f32_16x16x32_bf16(af[i], bfv[jj],
                                                                acc[i][jh * 4 + jj], 0, 0, 0);
        }
        __syncthreads();
    }

    // ---- epilogue: packed corr0 stores + in-register level-1 pool ----
    const float scale = 0.0625f;  // 1/sqrt(256)
    const int s15  = lane & 15;
    const int even = (lane & 1) == 0;
    for (int i = 0; i < 2; i++) {
        for (int r = 0; r < 4; r++) {
            int rp = m0 + w * 32 + i * 16 + ((lane >> 4) & 3) * 4 + r;   // global p-row
            size_t rb0 = ((size_t)bz * P_ + rp) * 2048;                  // corr0 u32 base
            size_t rb1 = ((size_t)bz * P_ + rp) * 1024 + bx * 32;        // corr1 base
            for (int j = 0; j < 4; j++) {
                float v0 = acc[i][j][r] * scale;       // col cj = j*16 + s15
                float v1 = acc[i][j + 4][r] * scale;   // col cj + 64
                float v0n = __shfl_xor(v0, 1);
                float v1n = __shfl_xor(v1, 1);
                // corr0: even lane packs (c,c+1); odd lane packs (c+64-1? -> c+63..):
                unsigned int u = even ? (f2bf(v0) | (f2bf(v0n) << 16))
                                      : (f2bf(v1n) | (f2bf(v1) << 16));
                int colu = even ? ((n0 + j * 16 + s15) >> 1)
                                : ((n0 + j * 16 + 64 + s15 - 1) >> 1);
                C0[rb0 + colu] = u;
                // level-1 pool: quad (c, c+1, c+64, c+65)
                if (even) {
                    float s4 = (v0 + v0n + v1 + v1n) * 0.25f;
                    C1[rb1 + ((j * 16 + s15) >> 1)] = (unsigned short)f2bf(s4);
                }
            }
        }
    }
}

// ---------------- pyramid tail: corr1 -> corr2 -> corr3, one block per (b,p) ----------------
__global__ __launch_bounds__(256) void pyr23(const unsigned int* __restrict__ c1,
                                             unsigned int* __restrict__ c2,
                                             unsigned int* __restrict__ c3) {
    __shared__ unsigned int L1[512];    // 32x32 bf16 (16 uints/row)
    __shared__ unsigned int L2[128];    // 16x16 (8 uints/row)
    const int bp = blockIdx.x;
    const int tid = threadIdx.x;
    L1[tid]       = c1[(size_t)bp * 512 + tid];
    L1[tid + 256] = c1[(size_t)bp * 512 + tid + 256];
    __syncthreads();
    if (tid < 128) {
        int x = tid & 7, y = tid >> 3;
        unsigned int a  = L1[(2 * y) * 16 + 2 * x];
        unsigned int a2 = L1[(2 * y) * 16 + 2 * x + 1];
        unsigned int b  = L1[(2 * y + 1) * 16 + 2 * x];
        unsigned int b2 = L1[(2 * y + 1) * 16 + 2 * x + 1];
        float s0 = 0.25f * (bf2f(a & 0xffff) + bf2f(a >> 16) + bf2f(b & 0xffff) + bf2f(b >> 16));
        float s1 = 0.25f * (bf2f(a2 & 0xffff) + bf2f(a2 >> 16) + bf2f(b2 & 0xffff) + bf2f(b2 >> 16));
        unsigned int u = f2bf(s0) | (f2bf(s1) << 16);
        L2[tid] = u;
        c2[(size_t)bp * 128 + tid] = u;
    }
    __syncthreads();
    if (tid < 32) {
        int x = tid & 3, y = tid >> 2;
        unsigned int a  = L2[(2 * y) * 8 + 2 * x];
        unsigned int a2 = L2[(2 * y) * 8 + 2 * x + 1];
        unsigned int b  = L2[(2 * y + 1) * 8 + 2 * x];
        unsigned int b2 = L2[(2 * y + 1) * 8 + 2 * x + 1];
        float s0 = 0.25f * (bf2f(a & 0xffff) + bf2f(a >> 16) + bf2f(b & 0xffff) + bf2f(b >> 16));
        float s1 = 0.25f * (bf2f(a2 & 0xffff) + bf2f(a2 >> 16) + bf2f(b2 & 0xffff) + bf2f(b2 >> 16));
        c3[(size_t)bp * 32 + tid] = f2bf(s0) | (f2bf(s1) << 16);
    }
}

// ---------------- bilinear pyramid sampling, one block per (b,h,w) ----------------
__global__ __launch_bounds__(256) void sample_k(const unsigned short* __restrict__ c0,
                                                const unsigned short* __restrict__ c1,
                                                const unsigned short* __restrict__ c2,
                                                const unsigned short* __restrict__ c3,
                                                const float* __restrict__ coords,
                                                float* __restrict__ outp) {
    __shared__ unsigned short sl16[5680];  // 66*64 + 34*32 + 18*16 + 10*8
    __shared__ float cs[16];
    __shared__ float2 xt[288];             // {fx, bits: x0 | x1<<8}
    __shared__ float2 yt[288];             // {fy, bits: (base+y0*pw) | (base+y1*pw)<<16}
    __shared__ unsigned int ctb[324];      // (l*9+i9)<<8 | (l*9+j9)

    const int bp = blockIdx.x;     // b*4096 + p
    const int b  = bp >> 12;
    const int p  = bp & 4095;
    const int tid = threadIdx.x;
    unsigned int* slu = (unsigned int*)sl16;

    {
        const uint2* g0 = (const uint2*)(c0 + (size_t)bp * 4096);  // 1024 uint2
        for (int i = tid; i < 1024; i += 256) {
            uint2 v = g0[i];
            int e = 4 * i;
            int y = e >> 6, x = e & 63;
            int u = (y * 66 + x) >> 1;
            slu[u] = v.x; slu[u + 1] = v.y;
        }
        const unsigned int* g1 = (const unsigned int*)(c1 + (size_t)bp * 1024);  // 512 uints
        for (int i = tid; i < 512; i += 256)
            slu[2112 + (i >> 4) * 17 + (i & 15)] = g1[i];
        if (tid < 128)
            slu[2656 + (tid >> 3) * 9 + (tid & 7)] =
                ((const unsigned int*)(c2 + (size_t)bp * 256))[tid];
        if (tid < 32)
            slu[2800 + (tid >> 2) * 5 + (tid & 3)] =
                ((const unsigned int*)(c3 + (size_t)bp * 64))[tid];
        if (tid < 16) cs[tid] = coords[(size_t)(b * 16 + tid) * 4096 + p];
    }
    __syncthreads();

    for (int t = tid; t < 324; t += 256) {
        if (t < 288) {
            int n = t / 36, rem = t - n * 36;
            int l = rem / 9, dd = rem - l * 9;
            int wl = 64 >> l;
            int pw   = (l == 0) ? 66 : (l == 1) ? 34 : (l == 2) ? 18 : 10;
            int base = (l == 0) ? 0  : (l == 1) ? 4224 : (l == 2) ? 5312 : 5600;
            float inv = 1.0f / (float)(1 << l);
            float mx = (float)(wl - 1);
            float cx = cs[n * 2 + 0], cy = cs[n * 2 + 1];
            float xx = fminf(fmaxf(cx * inv + (float)(dd - 4), 0.0f), mx);
            float yy = fminf(fmaxf(cy * inv + (float)(dd - 4), 0.0f), mx);
            float x0f = floorf(xx), y0f = floorf(yy);
            int x0 = (int)x0f, y0 = (int)y0f;
            int x1 = min(x0 + 1, wl - 1), y1 = min(y0 + 1, wl - 1);
            unsigned int xb = (unsigned int)x0 | ((unsigned int)x1 << 8);
            unsigned int yb = (unsigned int)(base + y0 * pw)
                            | ((unsigned int)(base + y1 * pw) << 16);
            xt[t] = make_float2(xx - x0f, __uint_as_float(xb));
            yt[t] = make_float2(yy - y0f, __uint_as_float(yb));
        }
        int c = t;
        int l = c / 81, k = c - l * 81;
        int i9 = k / 9, j9 = k - i9 * 9;
        ctb[c] = ((unsigned int)(l * 9 + i9) << 8) | (unsigned int)(l * 9 + j9);
    }
    __syncthreads();

    // main loop with incremental (n, c) bookkeeping (no per-iter divide)
    const size_t outbase = (size_t)b * ((size_t)N_ * P_ * 324) + (size_t)p * 324;
    int n = 0, c = tid;   // tid < 256 < 324
    for (int o = tid; o < OUTC; o += 256) {
        unsigned int cv = ctb[c];
        int tb = n * 36;
        float2 xv = xt[tb + (cv >> 8)];
        float2 yv = yt[tb + (cv & 255)];
        unsigned int xb = __float_as_uint(xv.y);
        unsigned int yb = __float_as_uint(yv.y);
        int x0 = xb & 255, x1 = xb >> 8;
        int r0 = yb & 0xffff, r1 = yb >> 16;
        float fx = xv.x, fy = yv.x;
        float v00 = bf2f(sl16[r0 + x0]);
        float v01 = bf2f(sl16[r0 + x1]);
        float v10 = bf2f(sl16[r1 + x0]);
        float v11 = bf2f(sl16[r1 + x1]);
        float vx0 = v00 + fx * (v01 - v00);
        float vx1 = v10 + fx * (v11 - v10);
        float v   = vx0 + fy * (vx1 - vx0);
        outp[outbase + (size_t)n * (324 * 4095) + o] = v;
        c += 256;
        if (c >= 324) { c -= 324; n++; }
    }
}

extern "C" void kernel_launch(void* const* d_in, const int* in_sizes, int n_in,
                              void* d_out, int out_size, void* d_ws, size_t ws_size,
                              hipStream_t stream) {
    const float* fmap1  = (const float*)d_in[0];
    const float* fmap2  = (const float*)d_in[1];
    const float* coords = (const float*)d_in[2];
    float* out = (float*)d_out;

    char* ws = (char*)d_ws;
    size_t off = 0;
    auto alloc = [&](size_t bytes) {
        void* ptr = ws + off;
        off += (bytes + 255) & ~(size_t)255;
        return ptr;
    };
    __hip_bfloat16* f1t = (__hip_bfloat16*)alloc((size_t)B_ * P_ * C_ * 2);
    __hip_bfloat16* f2t = (__hip_bfloat16*)alloc((size_t)B_ * P_ * C_ * 2);
    unsigned short* corr0 = (unsigned short*)alloc((size_t)B_ * P_ * 4096 * 2);
    unsigned short* corr1 = (unsigned short*)alloc((size_t)B_ * P_ * 1024 * 2);
    unsigned short* corr2 = (unsigned short*)alloc((size_t)B_ * P_ * 256 * 2);
    unsigned short* corr3 = (unsigned short*)alloc((size_t)B_ * P_ * 64 * 2);

    conv_both<<<dim3(128, 8, 2 * B_), dim3(32, 8), 0, stream>>>(fmap1, fmap2, f1t, f2t);

    gemm_corr<<<dim3(2048), dim3(256), 0, stream>>>(f1t, f2t,
                                                    (unsigned int*)corr0, corr1);

    pyr23<<<dim3(B_ * P_), dim3(256), 0, stream>>>((const unsigned int*)corr1,
                                                   (unsigned int*)corr2,
                                                   (unsigned int*)corr3);

    sample_k<<<dim3(B_ * P_), dim3(256), 0, stream>>>(corr0, corr1, corr2, corr3, coords, out);
}

// Round 8
// 160.123 us; speedup vs baseline: 1.4211x; 1.0985x over previous
//
#include <hip/hip_runtime.h>
#include <hip/hip_bf16.h>
#include <stdint.h>

#define B_   2
#define C_   256
#define P_   4096   // H*W = 64*64
#define N_   8
#define OUTC 2592   // N_ * 324

typedef __bf16 bf16x8 __attribute__((ext_vector_type(8)));
typedef float floatx4 __attribute__((ext_vector_type(4)));

__device__ __forceinline__ float bf2f(unsigned int u16) {
    union { unsigned int i; float f; } x; x.i = u16 << 16; return x.f;
}
__device__ __forceinline__ unsigned int f2bf(float f) {
    union { float f; unsigned int i; } x; x.f = f;
    unsigned int u = x.i + 0x7FFFu + ((x.i >> 16) & 1u);  // RNE
    return u >> 16;
}

// ---------------- fmaps (B,C,P) fp32 -> (B,P,C) bf16, both in one dispatch ----------------
__global__ void conv_both(const float* __restrict__ in1, const float* __restrict__ in2,
                          __hip_bfloat16* __restrict__ out1, __hip_bfloat16* __restrict__ out2) {
    __shared__ float tile[32][33];
    int which = blockIdx.z >> 1;
    int b  = blockIdx.z & 1;
    const float* in = which ? in2 : in1;
    __hip_bfloat16* out = which ? out2 : out1;
    int p0 = blockIdx.x * 32;
    int c0 = blockIdx.y * 32;
    int tx = threadIdx.x;   // 0..31
    int ty0 = threadIdx.y;  // 0..7
    const float* ip = in + ((size_t)b * C_ + c0) * P_ + p0;
    for (int r = 0; r < 4; r++) {
        int ty = ty0 + r * 8;
        tile[ty][tx] = ip[(size_t)ty * P_ + tx];
    }
    __syncthreads();
    __hip_bfloat16* op = out + ((size_t)b * P_ + p0) * C_ + c0;
    for (int r = 0; r < 4; r++) {
        int ty = ty0 + r * 8;
        op[(size_t)ty * C_ + tx] = __float2bfloat16(tile[tx][ty]);
    }
}

// ---------------- corr GEMM (R6-proven structure): corr[p][q] = A[p]·B[q]/16, bf16 out ------
__global__ __launch_bounds__(256) void gemm_corr(const __hip_bfloat16* __restrict__ A,
                                                 const __hip_bfloat16* __restrict__ Bm,
                                                 unsigned short* __restrict__ Cmat) {
    __shared__ __align__(16) __hip_bfloat16 lA[128 * 32];
    __shared__ __align__(16) __hip_bfloat16 lB[128 * 32];
    const int id = blockIdx.x;           // 0..2047
    const int bz = id >> 10;
    const int r_ = id & 1023;
    const int s_ = r_ >> 3;
    const int by = (r_ & 7) * 4 + (s_ >> 5);
    const int bx = s_ & 31;
    const int m0 = by * 128;
    const int n0 = bx * 128;
    const __hip_bfloat16* Ab = A  + (size_t)bz * P_ * C_;
    const __hip_bfloat16* Bb = Bm + (size_t)bz * P_ * C_;
    unsigned short* Cb = Cmat + (size_t)bz * P_ * P_;

    const int tid  = threadIdx.x;
    const int lane = tid & 63;
    const int w    = tid >> 6;       // 0..3
    const int wm   = w & 1, wn = w >> 1;

    floatx4 acc[4][4];
    for (int i = 0; i < 4; i++)
        for (int j = 0; j < 4; j++)
            acc[i][j] = floatx4{0.f, 0.f, 0.f, 0.f};

    const int srow = w * 16 + (lane >> 2);
    const int scol = (lane & 3) * 8;

    for (int k0 = 0; k0 < C_; k0 += 32) {
        for (int j = 0; j < 2; j++) {
            int row = j * 64 + srow;
            const __hip_bfloat16* ga = Ab + (size_t)(m0 + row) * C_ + k0 + scol;
            const __hip_bfloat16* gb = Bb + (size_t)(n0 + row) * C_ + k0 + scol;
            __hip_bfloat16* la = lA + (j * 64 + w * 16) * 32;
            __hip_bfloat16* lb = lB + (j * 64 + w * 16) * 32;
            __builtin_amdgcn_global_load_lds((const __attribute__((address_space(1))) void*)ga,
                                             (__attribute__((address_space(3))) void*)la, 16, 0, 0);
            __builtin_amdgcn_global_load_lds((const __attribute__((address_space(1))) void*)gb,
                                             (__attribute__((address_space(3))) void*)lb, 16, 0, 0);
        }
        __syncthreads();
        const int kq   = (lane >> 4) * 8;
        const int rsel = lane & 15;
        bf16x8 af[4], bfv[4];
        for (int i = 0; i < 4; i++) {
            af[i]  = *(const bf16x8*)&lA[(wm * 64 + i * 16 + rsel) * 32 + kq];
            bfv[i] = *(const bf16x8*)&lB[(wn * 64 + i * 16 + rsel) * 32 + kq];
        }
        for (int i = 0; i < 4; i++)
            for (int j = 0; j < 4; j++)
                acc[i][j] = __builtin_amdgcn_mfma_f32_16x16x32_bf16(af[i], bfv[j], acc[i][j], 0, 0, 0);
        __syncthreads();
    }

    const float scale = 0.0625f;  // 1/sqrt(256)
    const int colb  = n0 + wn * 64 + (lane & 15);
    const int rbase = m0 + wm * 64 + ((lane >> 4) * 4);
    for (int i = 0; i < 4; i++)
        for (int j = 0; j < 4; j++)
            for (int r = 0; r < 4; r++)
                Cb[(size_t)(rbase + i * 16 + r) * P_ + colb + j * 16] =
                    (unsigned short)f2bf(acc[i][j][r] * scale);
}

// ---------------- pyramid + bilinear sampling fused, one block per (b,h,w) ----------------
// Stages the 64x64 bf16 level-0 row into padded LDS, pools levels 1-3 IN LDS
// (no corr1/2/3 global round-trip), then samples. Strides 66/34/18/10 shorts
// (odd uint stride -> conflict-free); all pool accesses uint-aligned.
__global__ __launch_bounds__(256) void sample_k(const unsigned short* __restrict__ c0,
                                                const float* __restrict__ coords,
                                                float* __restrict__ outp) {
    __shared__ unsigned short sl16[5680];  // 66*64 | 34*32 @4224 | 18*16 @5312 | 10*8 @5600
    __shared__ float cs[16];
    __shared__ float2 xt[288];             // {fx, bits: x0 | x1<<8}
    __shared__ float2 yt[288];             // {fy, bits: (base+y0*pw) | (base+y1*pw)<<16}
    __shared__ unsigned int ctb[324];      // (l*9+i9)<<8 | (l*9+j9)

    const int bp = blockIdx.x;     // b*4096 + p
    const int b  = bp >> 12;
    const int p  = bp & 4095;
    const int tid = threadIdx.x;
    unsigned int* slu = (unsigned int*)sl16;

    // ---- stage level-0 row (bf16, padded stride 66) + coords ----
    {
        const uint2* g0 = (const uint2*)(c0 + (size_t)bp * 4096);  // 1024 uint2
        for (int i = tid; i < 1024; i += 256) {
            uint2 v = g0[i];
            int e = 4 * i;
            int y = e >> 6, x = e & 63;
            int u = (y * 66 + x) >> 1;
            slu[u] = v.x; slu[u + 1] = v.y;
        }
        if (tid < 16) cs[tid] = coords[(size_t)(b * 16 + tid) * 4096 + p];
    }
    __syncthreads();

    // ---- pool level 1 (32x32) from level 0; build tables concurrently ----
    for (int t = tid; t < 1024; t += 256) {
        int y = t >> 5, x = t & 31;
        unsigned int a = slu[y * 66 + x];          // row 2y,   cols 2x,2x+1
        unsigned int c = slu[y * 66 + 33 + x];     // row 2y+1, cols 2x,2x+1
        float s = 0.25f * (bf2f(a & 0xffff) + bf2f(a >> 16)
                         + bf2f(c & 0xffff) + bf2f(c >> 16));
        sl16[4224 + y * 34 + x] = (unsigned short)f2bf(s);
    }
    for (int t = tid; t < 324; t += 256) {
        if (t < 288) {
            int n = t / 36, rem = t - n * 36;
            int l = rem / 9, dd = rem - l * 9;
            int wl = 64 >> l;
            int pw   = (l == 0) ? 66 : (l == 1) ? 34 : (l == 2) ? 18 : 10;
            int base = (l == 0) ? 0  : (l == 1) ? 4224 : (l == 2) ? 5312 : 5600;
            float inv = 1.0f / (float)(1 << l);
            float mx = (float)(wl - 1);
            float cx = cs[n * 2 + 0], cy = cs[n * 2 + 1];
            float xx = fminf(fmaxf(cx * inv + (float)(dd - 4), 0.0f), mx);
            float yy = fminf(fmaxf(cy * inv + (float)(dd - 4), 0.0f), mx);
            float x0f = floorf(xx), y0f = floorf(yy);
            int x0 = (int)x0f, y0 = (int)y0f;
            int x1 = min(x0 + 1, wl - 1), y1 = min(y0 + 1, wl - 1);
            unsigned int xb = (unsigned int)x0 | ((unsigned int)x1 << 8);
            unsigned int yb = (unsigned int)(base + y0 * pw)
                            | ((unsigned int)(base + y1 * pw) << 16);
            xt[t] = make_float2(xx - x0f, __uint_as_float(xb));
            yt[t] = make_float2(yy - y0f, __uint_as_float(yb));
        }
        int c = t;
        int l = c / 81, k = c - l * 81;
        int i9 = k / 9, j9 = k - i9 * 9;
        ctb[c] = ((unsigned int)(l * 9 + i9) << 8) | (unsigned int)(l * 9 + j9);
    }
    __syncthreads();

    // ---- pool level 2 (16x16) from level 1 ----
    if (tid < 256) {
        int y = tid >> 4, x = tid & 15;
        unsigned int a = slu[2112 + 34 * y + x];       // L1 row 2y
        unsigned int c = slu[2112 + 34 * y + 17 + x];  // L1 row 2y+1
        float s = 0.25f * (bf2f(a & 0xffff) + bf2f(a >> 16)
                         + bf2f(c & 0xffff) + bf2f(c >> 16));
        sl16[5312 + y * 18 + x] = (unsigned short)f2bf(s);
    }
    __syncthreads();

    // ---- pool level 3 (8x8) from level 2 ----
    if (tid < 64) {
        int y = tid >> 3, x = tid & 7;
        unsigned int a = slu[2656 + 18 * y + x];       // L2 row 2y
        unsigned int c = slu[2656 + 18 * y + 9 + x];   // L2 row 2y+1
        float s = 0.25f * (bf2f(a & 0xffff) + bf2f(a >> 16)
                         + bf2f(c & 0xffff) + bf2f(c >> 16));
        sl16[5600 + y * 10 + x] = (unsigned short)f2bf(s);
    }
    __syncthreads();

    // ---- main loop: 2592 outputs, incremental (n,c) bookkeeping ----
    const size_t outbase = (size_t)b * ((size_t)N_ * P_ * 324) + (size_t)p * 324;
    int n = 0, c = tid;   // tid < 256 < 324
    for (int o = tid; o < OUTC; o += 256) {
        unsigned int cv = ctb[c];
        int tb = n * 36;
        float2 xv = xt[tb + (cv >> 8)];
        float2 yv = yt[tb + (cv & 255)];
        unsigned int xb = __float_as_uint(xv.y);
        unsigned int yb = __float_as_uint(yv.y);
        int x0 = xb & 255, x1 = xb >> 8;
        int r0 = yb & 0xffff, r1 = yb >> 16;
        float fx = xv.x, fy = yv.x;
        float v00 = bf2f(sl16[r0 + x0]);
        float v01 = bf2f(sl16[r0 + x1]);
        float v10 = bf2f(sl16[r1 + x0]);
        float v11 = bf2f(sl16[r1 + x1]);
        float vx0 = v00 + fx * (v01 - v00);
        float vx1 = v10 + fx * (v11 - v10);
        float v   = vx0 + fy * (vx1 - vx0);
        outp[outbase + (size_t)n * (324 * 4095) + o] = v;
        c += 256;
        if (c >= 324) { c -= 324; n++; }
    }
}

extern "C" void kernel_launch(void* const* d_in, const int* in_sizes, int n_in,
                              void* d_out, int out_size, void* d_ws, size_t ws_size,
                              hipStream_t stream) {
    const float* fmap1  = (const float*)d_in[0];
    const float* fmap2  = (const float*)d_in[1];
    const float* coords = (const float*)d_in[2];
    float* out = (float*)d_out;

    char* ws = (char*)d_ws;
    size_t off = 0;
    auto alloc = [&](size_t bytes) {
        void* ptr = ws + off;
        off += (bytes + 255) & ~(size_t)255;
        return ptr;
    };
    __hip_bfloat16* f1t = (__hip_bfloat16*)alloc((size_t)B_ * P_ * C_ * 2);
    __hip_bfloat16* f2t = (__hip_bfloat16*)alloc((size_t)B_ * P_ * C_ * 2);
    unsigned short* corr0 = (unsigned short*)alloc((size_t)B_ * P_ * 4096 * 2);

    conv_both<<<dim3(128, 8, 2 * B_), dim3(32, 8), 0, stream>>>(fmap1, fmap2, f1t, f2t);

    gemm_corr<<<dim3(2048), dim3(256), 0, stream>>>(f1t, f2t, corr0);

    sample_k<<<dim3(B_ * P_), dim3(256), 0, stream>>>(corr0, coords, out);
}